// Round 6
// baseline (470.315 us; speedup 1.0000x reference)
//
#include <hip/hip_runtime.h>
#include <hip/hip_fp16.h>

#define B 32
#define NW2V 300
#define NR 200
#define NBLK 256          // chunks for count/scatter passes
#define MAXNB 2048        // max coarse buckets
#define HWIN 32           // per-group window (gather burst depth)

// rT[h][j][b] = bias[j] + sum_k q[b][k] * W[k][j]  -> 3 x [N_R, B] fp32
__global__ void compute_r_all_kernel(const float* __restrict__ q,
                                     const float* __restrict__ W1, const float* __restrict__ b1,
                                     const float* __restrict__ W2, const float* __restrict__ b2,
                                     const float* __restrict__ W3, const float* __restrict__ b3,
                                     float* __restrict__ rT) {
    int h = blockIdx.x / 25;                       // 25 blocks per hop (NR*B/256)
    int tid = (blockIdx.x % 25) * 256 + threadIdx.x;
    if (tid >= NR * B) return;
    const float* W    = (h == 0) ? W1 : (h == 1) ? W2 : W3;
    const float* bias = (h == 0) ? b1 : (h == 1) ? b2 : b3;
    int b = tid & (B - 1);
    int j = tid >> 5;
    float acc = bias[j];
    for (int k = 0; k < NW2V; ++k)
        acc += q[b * NW2V + k] * W[k * NR + j];
    rT[h * NR * B + j * B + b] = acc;
}

// x [B, N_E] f32 -> xT [N_E, B] f16
__global__ void transpose_in_kernel(const float* __restrict__ x,
                                    __half* __restrict__ xT, int n_e) {
    __shared__ float tile[64][33];
    int e0 = blockIdx.x * 64;
    for (int p = 0; p < 8; ++p) {
        int idx = p * 256 + threadIdx.x;
        int b = idx >> 6, e = idx & 63;
        if (e0 + e < n_e) tile[e][b] = x[(size_t)b * n_e + e0 + e];
    }
    __syncthreads();
    for (int p = 0; p < 8; ++p) {
        int idx = p * 256 + threadIdx.x;
        int b = idx & 31, e = idx >> 5;
        if (e0 + e < n_e) xT[(size_t)(e0 + e) * B + b] = __float2half(tile[e][b]);
    }
}

// xT [N_E, B] f16 -> out [B, N_E] f32
__global__ void transpose_out_kernel(const __half* __restrict__ xT,
                                     float* __restrict__ out, int n_e) {
    __shared__ float tile[64][33];
    int e0 = blockIdx.x * 64;
    for (int p = 0; p < 8; ++p) {
        int idx = p * 256 + threadIdx.x;
        int b = idx & 31, e = idx >> 5;
        if (e0 + e < n_e) tile[e][b] = __half2float(xT[(size_t)(e0 + e) * B + b]);
    }
    __syncthreads();
    for (int p = 0; p < 8; ++p) {
        int idx = p * 256 + threadIdx.x;
        int b = idx >> 6, e = idx & 63;
        if (e0 + e < n_e) out[(size_t)b * n_e + e0 + e] = tile[e][b];
    }
}

// ---- two-level sort of triples by obj (shared by all 3 hops) ----

__global__ void count_kernel(const int* __restrict__ obj,
                             int* __restrict__ hist_bb, int n_t, int nb, int chunk) {
    __shared__ int h[MAXNB];
    for (int i = threadIdx.x; i < nb; i += 1024) h[i] = 0;
    __syncthreads();
    int t0 = blockIdx.x * chunk;
    int t1 = min(t0 + chunk, n_t);
    for (int t = t0 + threadIdx.x; t < t1; t += 1024)
        atomicAdd(&h[obj[t] >> 8], 1);
    __syncthreads();
    for (int i = threadIdx.x; i < nb; i += 1024)
        hist_bb[(size_t)i * NBLK + blockIdx.x] = h[i];
}

__global__ void block_reduce_kernel(const int* __restrict__ vals,
                                    int* __restrict__ blockSums, int len) {
    __shared__ int s[256];
    int i = blockIdx.x * 256 + threadIdx.x;
    s[threadIdx.x] = (i < len) ? vals[i] : 0;
    __syncthreads();
    for (int off = 128; off > 0; off >>= 1) {
        if (threadIdx.x < off) s[threadIdx.x] += s[threadIdx.x + off];
        __syncthreads();
    }
    if (threadIdx.x == 0) blockSums[blockIdx.x] = s[0];
}

__global__ void scan_blocksums_kernel(int* __restrict__ blockSums, int nb) {
    __shared__ int s[256];
    int t = threadIdx.x;
    int local[8];
    int run = 0;
    for (int c = 0; c < 8; ++c) {
        int j = t * 8 + c;
        run += (j < nb) ? blockSums[j] : 0;
        local[c] = run;
    }
    s[t] = run;
    __syncthreads();
    for (int off = 1; off < 256; off <<= 1) {
        int v = (t >= off) ? s[t - off] : 0;
        __syncthreads();
        s[t] += v;
        __syncthreads();
    }
    int threadExcl = s[t] - run;
    for (int c = 0; c < 8; ++c) {
        int j = t * 8 + c;
        if (j < nb) blockSums[j] = threadExcl + (c == 0 ? 0 : local[c - 1]);
    }
}

__global__ void scan_apply_kernel(const int* __restrict__ vals,
                                  const int* __restrict__ blockSums,
                                  int* __restrict__ out, int len) {
    __shared__ int s[256];
    int t = threadIdx.x;
    int i = blockIdx.x * 256 + t;
    int c = (i < len) ? vals[i] : 0;
    s[t] = c;
    __syncthreads();
    for (int off = 1; off < 256; off <<= 1) {
        int v = (t >= off) ? s[t - off] : 0;
        __syncthreads();
        s[t] += v;
        __syncthreads();
    }
    if (i < len) out[i] = blockSums[blockIdx.x] + s[t] - c;
}

// coarse scatter into 256-entity buckets; 1024 threads for latency hiding
__global__ void scatter8_kernel(const int* __restrict__ subj,
                                const int* __restrict__ rel,
                                const int* __restrict__ obj,
                                const int* __restrict__ base_bb,
                                uint2* __restrict__ packed2,
                                int n_t, int nb, int chunk) {
    __shared__ int h[MAXNB];
    __shared__ int sbase[MAXNB];
    for (int i = threadIdx.x; i < nb; i += 1024) {
        h[i] = 0;
        sbase[i] = base_bb[(size_t)i * NBLK + blockIdx.x];
    }
    __syncthreads();
    int t0 = blockIdx.x * chunk;
    int t1 = min(t0 + chunk, n_t);
    for (int t = t0 + threadIdx.x; t < t1; t += 1024) {
        int o = obj[t];
        int bin = o >> 8;
        int rank = atomicAdd(&h[bin], 1);
        packed2[sbase[bin] + rank] = make_uint2(
            (unsigned)subj[t] | ((unsigned)rel[t] << 19), (unsigned)o);
    }
}

// fine counting sort by obj&255 within each bucket -> fully obj-sorted
__global__ void fine_sort_kernel(const uint2* __restrict__ in,
                                 uint2* __restrict__ outp,
                                 const int* __restrict__ base_bb,
                                 int n_t, int nb) {
    __shared__ int cnt[256];
    __shared__ int cur[256];
    int bin = blockIdx.x;
    int beg = base_bb[(size_t)bin * NBLK];
    int end = (bin + 1 < nb) ? base_bb[(size_t)(bin + 1) * NBLK] : n_t;
    int t = threadIdx.x;
    cnt[t] = 0;
    __syncthreads();
    for (int i = beg + t; i < end; i += 256)
        atomicAdd(&cnt[in[i].y & 255], 1);
    __syncthreads();
    int c = cnt[t];
    __syncthreads();
    for (int off = 1; off < 256; off <<= 1) {
        int v = (t >= off) ? cnt[t - off] : 0;
        __syncthreads();
        cnt[t] += v;
        __syncthreads();
    }
    cur[t] = cnt[t] - c + beg;        // exclusive scan + bucket base
    __syncthreads();
    for (int i = beg + t; i < end; i += 256) {
        uint2 e = in[i];
        int pos = atomicAdd(&cur[e.y & 255], 1);
        outp[pos] = e;
    }
}

// Flat hop over SORTED triples, round-3 run-merged atomic flush (proven
// leanest inner loop; round-5's hybrid store/atomic was -10us from extra LDS
// neighbor reads + branches). ONE change vs round 3: per-group window is 32
// entries (xh[32] burst, 512 staged per block) -- the hop is latency/MLP
// bound (FETCH invariant across rounds 3/4/5 while time varied), so doubling
// outstanding gathers per wave halves the load-free accumulate gaps.
__global__ void hop_merge_kernel(const __half2* __restrict__ xT2,
                                 const float2* __restrict__ rT2,
                                 __half2* __restrict__ outT2,
                                 const uint2* __restrict__ sorted2,
                                 const int* __restrict__ n_hop,
                                 int hop, int n_e, int n_t) {
    int tid = threadIdx.x;
    if (*n_hop < hop) {               // degenerate: identity copy
        long total = (long)n_e * 16;
        for (long i = (long)blockIdx.x * 256 + tid; i < total;
             i += (long)gridDim.x * 256)
            outT2[i] = xT2[i];
        return;
    }
    __shared__ uint2 ent[512];
    int base = blockIdx.x * 512;
    int cnt = min(512, n_t - base);
    {
        int i0 = tid, i1 = tid + 256;
        ent[i0] = (i0 < cnt) ? sorted2[base + i0] : make_uint2(0u, 0xFFFFFFFFu);
        ent[i1] = (i1 < cnt) ? sorted2[base + i1] : make_uint2(0u, 0xFFFFFFFFu);
    }
    __syncthreads();
    int g = tid >> 4, l = tid & 15;   // 16 groups x 16 lanes
    int e0 = g * HWIN;
    int m = min(HWIN, cnt - e0);      // group-uniform
    if (m <= 0) return;

    __half2 xh[HWIN];
#pragma unroll
    for (int j = 0; j < HWIN; ++j) {  // 32 independent gathers, all in flight
        int s = (int)(ent[e0 + j].x & 0x7FFFF);
        xh[j] = xT2[(size_t)s * 16 + l];
    }

    float a0 = 0.f, a1 = 0.f;
    unsigned cur_o = ent[e0].y;
#pragma unroll
    for (int j = 0; j < HWIN; ++j) {
        if (j < m) {
            uint2 e = ent[e0 + j];
            float2 rf = rT2[(size_t)(e.x >> 19) * 16 + l];   // L1-resident
            float2 xf = __half22float2(xh[j]);
            if (e.y != cur_o) {                  // uniform within 16-lane group
                unsafeAtomicAdd(&outT2[(size_t)cur_o * 16 + l],
                                __floats2half2_rn(a0, a1));
                a0 = 0.f; a1 = 0.f;
                cur_o = e.y;
            }
            a0 += xf.x * rf.x;
            a1 += xf.y * rf.y;
        }
    }
    unsafeAtomicAdd(&outT2[(size_t)cur_o * 16 + l], __floats2half2_rn(a0, a1));
}

extern "C" void kernel_launch(void* const* d_in, const int* in_sizes, int n_in,
                              void* d_out, int out_size, void* d_ws, size_t ws_size,
                              hipStream_t stream) {
    const float* x    = (const float*)d_in[0];
    const float* q    = (const float*)d_in[1];
    const int*   subj = (const int*)d_in[2];
    const int*   rel  = (const int*)d_in[3];
    const int*   obj  = (const int*)d_in[4];
    const float* W1   = (const float*)d_in[5];
    const float* bb1  = (const float*)d_in[6];
    const float* W2   = (const float*)d_in[7];
    const float* bb2  = (const float*)d_in[8];
    const float* W3   = (const float*)d_in[9];
    const float* bb3  = (const float*)d_in[10];
    const int*   n_hop = (const int*)d_in[11];
    float* out = (float*)d_out;

    const int n_e   = in_sizes[0] / B;        // 500000
    const int n_t   = in_sizes[2];            // 2000000
    const int nb    = (n_e + 255) >> 8;       // 1954 coarse buckets
    const int chunk = (n_t + NBLK - 1) / NBLK;
    const int scanLen = nb * NBLK;            // 500224
    const int snb   = (scanLen + 255) / 256;  // 1954 (<= 2048)

    // ws layout (~102 MB of >=128 MB):
    char* w = (char*)d_ws;
    __half* bufA    = (__half*)w;                     w += 32000000;  // [N_E,B] f16
    __half* bufB    = (__half*)w;                     w += 32000000;  // [N_E,B] f16
    float*  rT      = (float*)w;                      w += 76800;     // 3*[N_R,B]
    int*    hist_bb = (int*)w;                        w += 2097152;   // [nb*NBLK]
    int*    base_bb = (int*)w;                        w += 2097152;   // [nb*NBLK]
    int*    bsums   = (int*)w;                        w += 16384;     // [snb]
    uint2*  packed2 = (uint2*)w;                      w += 16000000;  // [N_T]
    uint2*  sorted2 = (uint2*)w;                                      // [N_T]

    compute_r_all_kernel<<<75, 256, 0, stream>>>(q, W1, bb1, W2, bb2, W3, bb3, rT);

    const int tblocks = (n_e + 63) / 64;
    transpose_in_kernel<<<tblocks, 256, 0, stream>>>(x, bufA, n_e);

    // --- sort by obj (once) ---
    count_kernel<<<NBLK, 1024, 0, stream>>>(obj, hist_bb, n_t, nb, chunk);
    block_reduce_kernel<<<snb, 256, 0, stream>>>(hist_bb, bsums, scanLen);
    scan_blocksums_kernel<<<1, 256, 0, stream>>>(bsums, snb);
    scan_apply_kernel<<<snb, 256, 0, stream>>>(hist_bb, bsums, base_bb, scanLen);
    scatter8_kernel<<<NBLK, 1024, 0, stream>>>(subj, rel, obj, base_bb, packed2,
                                               n_t, nb, chunk);
    fine_sort_kernel<<<nb, 256, 0, stream>>>(packed2, sorted2, base_bb, n_t, nb);

    // --- 3 flat hops with run-merged atomics (32-deep gather burst) ---
    const int hblocks = (n_t + 511) / 512;    // 3907
    const size_t bytes = (size_t)n_e * B * sizeof(__half);

    hipMemsetAsync(bufB, 0, bytes, stream);
    hop_merge_kernel<<<hblocks, 256, 0, stream>>>((const __half2*)bufA,
        (const float2*)(rT + 0 * NR * B), (__half2*)bufB, sorted2, n_hop, 1, n_e, n_t);
    hipMemsetAsync(bufA, 0, bytes, stream);
    hop_merge_kernel<<<hblocks, 256, 0, stream>>>((const __half2*)bufB,
        (const float2*)(rT + 1 * NR * B), (__half2*)bufA, sorted2, n_hop, 2, n_e, n_t);
    hipMemsetAsync(bufB, 0, bytes, stream);
    hop_merge_kernel<<<hblocks, 256, 0, stream>>>((const __half2*)bufA,
        (const float2*)(rT + 2 * NR * B), (__half2*)bufB, sorted2, n_hop, 3, n_e, n_t);

    transpose_out_kernel<<<tblocks, 256, 0, stream>>>(bufB, out, n_e);
}

// Round 7
// 443.630 us; speedup vs baseline: 1.0602x; 1.0602x over previous
//
#include <hip/hip_runtime.h>
#include <hip/hip_fp16.h>

#define B 32
#define NW2V 300
#define NR 200
#define NBLK 256          // chunks for count/scatter passes
#define CBLOG 11          // coarse bucket = 2048 entities
#define CBSZ  2048
#define FNB   2048        // fine bins (11-bit counting sort)

// rT[h][j][b] = bias[j] + sum_k q[b][k] * W[k][j]  -> 3 x [N_R, B] fp32
__global__ void compute_r_all_kernel(const float* __restrict__ q,
                                     const float* __restrict__ W1, const float* __restrict__ b1,
                                     const float* __restrict__ W2, const float* __restrict__ b2,
                                     const float* __restrict__ W3, const float* __restrict__ b3,
                                     float* __restrict__ rT) {
    int h = blockIdx.x / 25;                       // 25 blocks per hop (NR*B/256)
    int tid = (blockIdx.x % 25) * 256 + threadIdx.x;
    if (tid >= NR * B) return;
    const float* W    = (h == 0) ? W1 : (h == 1) ? W2 : W3;
    const float* bias = (h == 0) ? b1 : (h == 1) ? b2 : b3;
    int b = tid & (B - 1);
    int j = tid >> 5;
    float acc = bias[j];
    for (int k = 0; k < NW2V; ++k)
        acc += q[b * NW2V + k] * W[k * NR + j];
    rT[h * NR * B + j * B + b] = acc;
}

// x [B, N_E] f32 -> xT [N_E, B] f16
__global__ void transpose_in_kernel(const float* __restrict__ x,
                                    __half* __restrict__ xT, int n_e) {
    __shared__ float tile[64][33];
    int e0 = blockIdx.x * 64;
    for (int p = 0; p < 8; ++p) {
        int idx = p * 256 + threadIdx.x;
        int b = idx >> 6, e = idx & 63;
        if (e0 + e < n_e) tile[e][b] = x[(size_t)b * n_e + e0 + e];
    }
    __syncthreads();
    for (int p = 0; p < 8; ++p) {
        int idx = p * 256 + threadIdx.x;
        int b = idx & 31, e = idx >> 5;
        if (e0 + e < n_e) xT[(size_t)(e0 + e) * B + b] = __float2half(tile[e][b]);
    }
}

// xT [N_E, B] f16 -> out [B, N_E] f32
__global__ void transpose_out_kernel(const __half* __restrict__ xT,
                                     float* __restrict__ out, int n_e) {
    __shared__ float tile[64][33];
    int e0 = blockIdx.x * 64;
    for (int p = 0; p < 8; ++p) {
        int idx = p * 256 + threadIdx.x;
        int b = idx & 31, e = idx >> 5;
        if (e0 + e < n_e) tile[e][b] = __half2float(xT[(size_t)(e0 + e) * B + b]);
    }
    __syncthreads();
    for (int p = 0; p < 8; ++p) {
        int idx = p * 256 + threadIdx.x;
        int b = idx >> 6, e = idx & 63;
        if (e0 + e < n_e) out[(size_t)b * n_e + e0 + e] = tile[e][b];
    }
}

// ---- two-level sort of triples by obj (shared by all 3 hops) ----
// Coarse bucket = 2048 entities (nb=245): runs per (bucket,chunk) avg 32
// entries = 256B -> scatter write amp ~1.25x (was 4 entries/32B/3.5x at
// 256-entity buckets, round-0 profile: 55MB written for 16MB payload).

__global__ void count_kernel(const int* __restrict__ obj,
                             int* __restrict__ hist_bb, int n_t, int nb, int chunk) {
    __shared__ int h[256];
    for (int i = threadIdx.x; i < nb; i += 1024) h[i] = 0;
    __syncthreads();
    int t0 = blockIdx.x * chunk;
    int t1 = min(t0 + chunk, n_t);
    for (int t = t0 + threadIdx.x; t < t1; t += 1024)
        atomicAdd(&h[obj[t] >> CBLOG], 1);
    __syncthreads();
    for (int i = threadIdx.x; i < nb; i += 1024)
        hist_bb[(size_t)i * NBLK + blockIdx.x] = h[i];
}

__global__ void block_reduce_kernel(const int* __restrict__ vals,
                                    int* __restrict__ blockSums, int len) {
    __shared__ int s[256];
    int i = blockIdx.x * 256 + threadIdx.x;
    s[threadIdx.x] = (i < len) ? vals[i] : 0;
    __syncthreads();
    for (int off = 128; off > 0; off >>= 1) {
        if (threadIdx.x < off) s[threadIdx.x] += s[threadIdx.x + off];
        __syncthreads();
    }
    if (threadIdx.x == 0) blockSums[blockIdx.x] = s[0];
}

__global__ void scan_blocksums_kernel(int* __restrict__ blockSums, int nb) {
    __shared__ int s[256];
    int t = threadIdx.x;
    int local[8];
    int run = 0;
    for (int c = 0; c < 8; ++c) {
        int j = t * 8 + c;
        run += (j < nb) ? blockSums[j] : 0;
        local[c] = run;
    }
    s[t] = run;
    __syncthreads();
    for (int off = 1; off < 256; off <<= 1) {
        int v = (t >= off) ? s[t - off] : 0;
        __syncthreads();
        s[t] += v;
        __syncthreads();
    }
    int threadExcl = s[t] - run;
    for (int c = 0; c < 8; ++c) {
        int j = t * 8 + c;
        if (j < nb) blockSums[j] = threadExcl + (c == 0 ? 0 : local[c - 1]);
    }
}

__global__ void scan_apply_kernel(const int* __restrict__ vals,
                                  const int* __restrict__ blockSums,
                                  int* __restrict__ out, int len) {
    __shared__ int s[256];
    int t = threadIdx.x;
    int i = blockIdx.x * 256 + t;
    int c = (i < len) ? vals[i] : 0;
    s[t] = c;
    __syncthreads();
    for (int off = 1; off < 256; off <<= 1) {
        int v = (t >= off) ? s[t - off] : 0;
        __syncthreads();
        s[t] += v;
        __syncthreads();
    }
    if (i < len) out[i] = blockSums[blockIdx.x] + s[t] - c;
}

// coarse scatter into 2048-entity buckets; 1024 threads for latency hiding
__global__ void scatter8_kernel(const int* __restrict__ subj,
                                const int* __restrict__ rel,
                                const int* __restrict__ obj,
                                const int* __restrict__ base_bb,
                                uint2* __restrict__ packed2,
                                int n_t, int nb, int chunk) {
    __shared__ int h[256];
    __shared__ int sbase[256];
    for (int i = threadIdx.x; i < nb; i += 1024) {
        h[i] = 0;
        sbase[i] = base_bb[(size_t)i * NBLK + blockIdx.x];
    }
    __syncthreads();
    int t0 = blockIdx.x * chunk;
    int t1 = min(t0 + chunk, n_t);
    for (int t = t0 + threadIdx.x; t < t1; t += 1024) {
        int o = obj[t];
        int bin = o >> CBLOG;
        int rank = atomicAdd(&h[bin], 1);
        packed2[sbase[bin] + rank] = make_uint2(
            (unsigned)subj[t] | ((unsigned)rel[t] << 19), (unsigned)o);
    }
}

// fine counting sort by obj&2047 within each 2048-entity bucket -> fully
// obj-sorted. 1024 threads (was 256: same latency-bound shape as round-0
// scatter8). LDS: cnt[2048]+cur[2048]+s[1024] = 20KB.
__global__ void fine_sort_kernel(const uint2* __restrict__ in,
                                 uint2* __restrict__ outp,
                                 const int* __restrict__ base_bb,
                                 int n_t, int nb) {
    __shared__ int cnt[FNB];
    __shared__ int cur[FNB];
    __shared__ int s[1024];
    int bin = blockIdx.x;
    int beg = base_bb[(size_t)bin * NBLK];
    int end = (bin + 1 < nb) ? base_bb[(size_t)(bin + 1) * NBLK] : n_t;
    int t = threadIdx.x;
    cnt[t] = 0;
    cnt[t + 1024] = 0;
    __syncthreads();
    for (int i = beg + t; i < end; i += 1024)
        atomicAdd(&cnt[in[i].y & (FNB - 1)], 1);
    __syncthreads();
    int c0 = cnt[2 * t], c1 = cnt[2 * t + 1];
    int run = c0 + c1;
    s[t] = run;
    __syncthreads();
    for (int off = 1; off < 1024; off <<= 1) {
        int v = (t >= off) ? s[t - off] : 0;
        __syncthreads();
        s[t] += v;
        __syncthreads();
    }
    int excl = s[t] - run;                 // exclusive prefix over thread pairs
    cur[2 * t]     = beg + excl;
    cur[2 * t + 1] = beg + excl + c0;
    __syncthreads();
    for (int i = beg + t; i < end; i += 1024) {
        uint2 e = in[i];
        int pos = atomicAdd(&cur[e.y & (FNB - 1)], 1);
        outp[pos] = e;
    }
}

// Flat hop over SORTED triples: EXACT round-3 structure (best measured:
// 57.9us/hop). 16-lane group, 16-entry window, run-merged f16x2 atomics.
// Hop is per-CU miss-queue x L3-latency bound (FETCH ~118MB invariant across
// 4 structural variants, rounds 3-6) -- do not touch.
__global__ void hop_merge_kernel(const __half2* __restrict__ xT2,
                                 const float2* __restrict__ rT2,
                                 __half2* __restrict__ outT2,
                                 const uint2* __restrict__ sorted2,
                                 const int* __restrict__ n_hop,
                                 int hop, int n_e, int n_t) {
    int tid = threadIdx.x;
    if (*n_hop < hop) {               // degenerate: identity copy
        long total = (long)n_e * 16;
        for (long i = (long)blockIdx.x * 256 + tid; i < total;
             i += (long)gridDim.x * 256)
            outT2[i] = xT2[i];
        return;
    }
    __shared__ uint2 ent[256];
    int base = blockIdx.x * 256;
    int cnt = min(256, n_t - base);
    ent[tid] = (tid < cnt) ? sorted2[base + tid]
                           : make_uint2(0u, 0xFFFFFFFFu);
    __syncthreads();
    int g = tid >> 4, l = tid & 15;
    int e0 = g * 16;
    int m = min(16, cnt - e0);        // group-uniform
    if (m <= 0) return;

    __half2 xh[16];
#pragma unroll
    for (int j = 0; j < 16; ++j) {    // independent gathers, all in flight
        int s = (int)(ent[e0 + j].x & 0x7FFFF);
        xh[j] = xT2[(size_t)s * 16 + l];
    }

    float a0 = 0.f, a1 = 0.f;
    unsigned cur_o = ent[e0].y;
#pragma unroll
    for (int j = 0; j < 16; ++j) {
        if (j < m) {
            uint2 e = ent[e0 + j];
            float2 rf = rT2[(size_t)(e.x >> 19) * 16 + l];   // L1-resident
            float2 xf = __half22float2(xh[j]);
            if (e.y != cur_o) {                  // uniform within 16-lane group
                unsafeAtomicAdd(&outT2[(size_t)cur_o * 16 + l],
                                __floats2half2_rn(a0, a1));
                a0 = 0.f; a1 = 0.f;
                cur_o = e.y;
            }
            a0 += xf.x * rf.x;
            a1 += xf.y * rf.y;
        }
    }
    unsafeAtomicAdd(&outT2[(size_t)cur_o * 16 + l], __floats2half2_rn(a0, a1));
}

extern "C" void kernel_launch(void* const* d_in, const int* in_sizes, int n_in,
                              void* d_out, int out_size, void* d_ws, size_t ws_size,
                              hipStream_t stream) {
    const float* x    = (const float*)d_in[0];
    const float* q    = (const float*)d_in[1];
    const int*   subj = (const int*)d_in[2];
    const int*   rel  = (const int*)d_in[3];
    const int*   obj  = (const int*)d_in[4];
    const float* W1   = (const float*)d_in[5];
    const float* bb1  = (const float*)d_in[6];
    const float* W2   = (const float*)d_in[7];
    const float* bb2  = (const float*)d_in[8];
    const float* W3   = (const float*)d_in[9];
    const float* bb3  = (const float*)d_in[10];
    const int*   n_hop = (const int*)d_in[11];
    float* out = (float*)d_out;

    const int n_e   = in_sizes[0] / B;        // 500000
    const int n_t   = in_sizes[2];            // 2000000
    const int nb    = (n_e + CBSZ - 1) >> CBLOG;   // 245 coarse buckets
    const int chunk = (n_t + NBLK - 1) / NBLK;
    const int scanLen = nb * NBLK;            // 62720
    const int snb   = (scanLen + 255) / 256;  // 245 (<= 2048)

    // ws layout (~102 MB of >=128 MB):
    char* w = (char*)d_ws;
    __half* bufA    = (__half*)w;                     w += 32000000;  // [N_E,B] f16
    __half* bufB    = (__half*)w;                     w += 32000000;  // [N_E,B] f16
    float*  rT      = (float*)w;                      w += 76800;     // 3*[N_R,B]
    int*    hist_bb = (int*)w;                        w += 2097152;   // [nb*NBLK]
    int*    base_bb = (int*)w;                        w += 2097152;   // [nb*NBLK]
    int*    bsums   = (int*)w;                        w += 16384;     // [snb]
    uint2*  packed2 = (uint2*)w;                      w += 16000000;  // [N_T]
    uint2*  sorted2 = (uint2*)w;                                      // [N_T]

    compute_r_all_kernel<<<75, 256, 0, stream>>>(q, W1, bb1, W2, bb2, W3, bb3, rT);

    const int tblocks = (n_e + 63) / 64;
    transpose_in_kernel<<<tblocks, 256, 0, stream>>>(x, bufA, n_e);

    // --- sort by obj (once) ---
    count_kernel<<<NBLK, 1024, 0, stream>>>(obj, hist_bb, n_t, nb, chunk);
    block_reduce_kernel<<<snb, 256, 0, stream>>>(hist_bb, bsums, scanLen);
    scan_blocksums_kernel<<<1, 256, 0, stream>>>(bsums, snb);
    scan_apply_kernel<<<snb, 256, 0, stream>>>(hist_bb, bsums, base_bb, scanLen);
    scatter8_kernel<<<NBLK, 1024, 0, stream>>>(subj, rel, obj, base_bb, packed2,
                                               n_t, nb, chunk);
    fine_sort_kernel<<<nb, 1024, 0, stream>>>(packed2, sorted2, base_bb, n_t, nb);

    // --- 3 flat hops with run-merged atomics ---
    const int hblocks = (n_t + 255) / 256;    // 7813
    const size_t bytes = (size_t)n_e * B * sizeof(__half);

    hipMemsetAsync(bufB, 0, bytes, stream);
    hop_merge_kernel<<<hblocks, 256, 0, stream>>>((const __half2*)bufA,
        (const float2*)(rT + 0 * NR * B), (__half2*)bufB, sorted2, n_hop, 1, n_e, n_t);
    hipMemsetAsync(bufA, 0, bytes, stream);
    hop_merge_kernel<<<hblocks, 256, 0, stream>>>((const __half2*)bufB,
        (const float2*)(rT + 1 * NR * B), (__half2*)bufA, sorted2, n_hop, 2, n_e, n_t);
    hipMemsetAsync(bufB, 0, bytes, stream);
    hop_merge_kernel<<<hblocks, 256, 0, stream>>>((const __half2*)bufA,
        (const float2*)(rT + 2 * NR * B), (__half2*)bufB, sorted2, n_hop, 3, n_e, n_t);

    transpose_out_kernel<<<tblocks, 256, 0, stream>>>(bufB, out, n_e);
}